// Round 7
// baseline (1101.980 us; speedup 1.0000x reference)
//
#include <hip/hip_runtime.h>

#define DIMN 8192
#define SEQ  1024
#define NHEAD 128

typedef __attribute__((ext_vector_type(8))) short bf16x8;
typedef __attribute__((ext_vector_type(4))) float f32x4;

#define MFMA16(a, b, c) __builtin_amdgcn_mfma_f32_16x16x32_bf16((a), (b), (c), 0, 0, 0)

#define VMCNT2()  asm volatile("s_waitcnt vmcnt(2)" ::: "memory")
#define VMCNT0()  asm volatile("s_waitcnt vmcnt(0)" ::: "memory")
#define LGKM0()   asm volatile("s_waitcnt lgkmcnt(0)" ::: "memory")

__device__ __forceinline__ unsigned short f2bf(float f) {
  unsigned u = __float_as_uint(f);
  return (unsigned short)((u + 0x7FFFu + ((u >> 16) & 1u)) >> 16);
}
__device__ __forceinline__ unsigned pack2(float a, float b) {
  return (unsigned)f2bf(a) | ((unsigned)f2bf(b) << 16);
}
__device__ __forceinline__ unsigned pack2_rhu(float lo, float hi) {
  unsigned a = __float_as_uint(lo) + 0x8000u;
  unsigned b = __float_as_uint(hi) + 0x8000u;
  return (a >> 16) | (b & 0xFFFF0000u);
}
__device__ __forceinline__ void async_copy16(void* lds_dst, const void* gsrc) {
  __builtin_amdgcn_global_load_lds(
      (const __attribute__((address_space(1))) unsigned int*)gsrc,
      (__attribute__((address_space(3))) unsigned int*)lds_dst, 16, 0, 0);
}

// ---------------- fp32 -> bf16 convert (x) ----------------
__global__ __launch_bounds__(256) void cvt_bf16_kernel(
    const float* __restrict__ in, unsigned short* __restrict__ out) {
  int i = blockIdx.x * 256 + threadIdx.x;
  const float4* p = (const float4*)in;
  float4 a = p[2 * i];
  float4 b = p[2 * i + 1];
  uint4 r;
  r.x = pack2(a.x, a.y);
  r.y = pack2(a.z, a.w);
  r.z = pack2(b.x, b.y);
  r.w = pack2(b.z, b.w);
  ((uint4*)out)[i] = r;
}

// ---------------- GEMM: C[1024,8192] = A(bf16) @ W(f32->bf16) ----------------
// 128x256 tile, BK=64, 512 thr = 8 waves (2Mx4N, 64x64 out each), 16x16x32 MFMA.
// ROUND-6 DIAGNOSIS: latency-bound; B-loads depth-limited (128 B/wave in flight
// -> Little's law = measured 710 GB/s). FIX: (1) float4 B-loads (512 B/wave in
// flight), (2) 2-phase/K-tile m201-style schedule: {8 ds_read; issue staging;
// barrier; lgkm0; setprio+16 MFMA; post-MFMA vmcnt+ds_write; barrier} so the
// vmcnt drain sits after an MFMA cluster, not right after issue.
// 3-deep LDS buffers (144KB, 1 block/CU). Per-wave VMEM FIFO per iter t:
//   enter with [A(t+1)x2]; p0 issues B(t+1)x8(float4), A(t+2)x2 -> 12;
//   p1 post-MFMA vmcnt(2): drains A(t+1),B(t+1); leaves A(t+2). Never 0 in-loop.
// B LDS swizzle: slot p = w ^ (n&7) ^ ((n>>3)&7) -> per-8-lane groups tile all
// 8 slots on BOTH write (4-aligned col ownership) and read (16 consecutive rows).
template <int WRITE_F32>
__global__ __launch_bounds__(512, 2) void gemm_bf16(
    const unsigned short* __restrict__ A, const float* __restrict__ W,
    void* __restrict__ Cout, float out_scale) {
  __shared__ unsigned short smem[3 * 24576];  // per buf: A[128][64] + B_t[256][64]
  const int t = threadIdx.x;
  const int l = t & 63;
  const int w = t >> 6;
  const int wm = w >> 2, wn = w & 3;
  const int logical = (blockIdx.x & 7) * 32 + (blockIdx.x >> 3);  // XCD swizzle
  const int m0 = (logical & 7) * 128;
  const int n0 = (logical >> 3) * 256;

  const int rin = l >> 3;
  const int aslot = (l & 7) ^ rin;

  f32x4 acc[4][4];
#pragma unroll
  for (int mb = 0; mb < 4; ++mb)
#pragma unroll
    for (int nb = 0; nb < 4; ++nb) acc[mb][nb] = (f32x4){0.f, 0.f, 0.f, 0.f};

  float fb[8][4];  // 8 k-rows x 4 cols (one float4 each), static indices only
  const unsigned short* aptr = A + (size_t)(m0 + w * 16 + rin) * DIMN + aslot * 8;
  const float* wpF = W + (size_t)(w * 8) * DIMN + n0 + l * 4;  // wave w: k-rows w*8..w*8+7

  auto load_B4 = [&]() {  // 8 coalesced float4 loads (1 KB/wave each), advance
#pragma unroll
    for (int i = 0; i < 8; ++i)
      *(float4*)&fb[i][0] = *(const float4*)(wpF + (size_t)i * DIMN);
    wpF += (size_t)64 * DIMN;
  };
  auto write_B4 = [&](int buf) {  // 4 ds_write_b128, conflict-free swizzle
    unsigned short* bb = &smem[buf * 24576 + 8192];
#pragma unroll
    for (int j = 0; j < 4; ++j) {
      int n = l * 4 + j;
      int p = w ^ (n & 7) ^ ((n >> 3) & 7);
      uint4 val;
      val.x = pack2_rhu(fb[0][j], fb[1][j]);
      val.y = pack2_rhu(fb[2][j], fb[3][j]);
      val.z = pack2_rhu(fb[4][j], fb[5][j]);
      val.w = pack2_rhu(fb[6][j], fb[7][j]);
      *(uint4*)&bb[n * 64 + p * 8] = val;
    }
  };
  auto stage_A = [&](int buf) {  // 2 gload_lds (A is bf16, linear dest), advance
#pragma unroll
    for (int i = 0; i < 2; ++i)
      async_copy16(&smem[buf * 24576 + (w * 16 + i * 8) * 64], aptr + (size_t)i * 8 * DIMN);
    aptr += 64;
  };

// PHASE: ds_read subtile -> PRE (issue staging) -> barrier -> lgkm0+schedbar ->
//        setprio(1) 16 MFMA setprio(0) -> POST (vmcnt + ds_write + lgkm0) -> barrier
#define PHASE(BUF_, KH_, PRE, POST)                                        \
  do {                                                                     \
    const unsigned short* la_ = &smem[(BUF_) * 24576];                     \
    const unsigned short* lb_ = la_ + 8192;                                \
    bf16x8 af_[4], bf_[4];                                                 \
    _Pragma("unroll")                                                      \
    for (int mb = 0; mb < 4; ++mb) {                                       \
      int row = wm * 64 + mb * 16 + (l & 15);                              \
      int sl = ((l >> 4) + (KH_) * 4) ^ (row & 7);                         \
      af_[mb] = *(const bf16x8*)&la_[row * 64 + sl * 8];                   \
    }                                                                      \
    _Pragma("unroll")                                                      \
    for (int nb = 0; nb < 4; ++nb) {                                       \
      int row = wn * 64 + nb * 16 + (l & 15);                              \
      int sl = ((l >> 4) + (KH_) * 4) ^ (row & 7) ^ ((row >> 3) & 7);      \
      bf_[nb] = *(const bf16x8*)&lb_[row * 64 + sl * 8];                   \
    }                                                                      \
    PRE;                                                                   \
    __builtin_amdgcn_s_barrier();                                          \
    asm volatile("s_waitcnt lgkmcnt(0)" ::: "memory");                     \
    __builtin_amdgcn_sched_barrier(0);                                     \
    __builtin_amdgcn_s_setprio(1);                                         \
    _Pragma("unroll")                                                      \
    for (int mb = 0; mb < 4; ++mb)                                         \
      _Pragma("unroll")                                                    \
      for (int nb = 0; nb < 4; ++nb)                                       \
        acc[mb][nb] = MFMA16(af_[mb], bf_[nb], acc[mb][nb]);               \
    __builtin_amdgcn_s_setprio(0);                                         \
    POST;                                                                  \
    __builtin_amdgcn_s_barrier();                                          \
  } while (0)

  // prologue: tile0 staged; A(1) DMA in flight
  load_B4();                 // [B0 x8]
  stage_A(0);                // [B0, A0 x2]
  stage_A(1);                // [B0, A0, A1 x2]
  VMCNT2();                  // B0+A0 done; A1 in flight
  write_B4(0);
  LGKM0();
  __builtin_amdgcn_s_barrier();

#define CSTEP(B0_, B1_, B2_)                                    \
  PHASE(B0_, 0, { load_B4(); stage_A(B2_); }, {});              \
  PHASE(B0_, 1, {}, { VMCNT2(); write_B4(B1_); LGKM0(); })

  for (int it = 0; it < 42; ++it) {   // t = 0..125
    CSTEP(0, 1, 2);
    CSTEP(1, 2, 0);
    CSTEP(2, 0, 1);
  }
  // t = 126 (buf0): no A-stage (t+2 == 128)
  PHASE(0, 0, { load_B4(); }, {});
  PHASE(0, 1, {}, { VMCNT0(); write_B4(1); LGKM0(); });
  // t = 127 (buf1)
  PHASE(1, 0, {}, {});
  PHASE(1, 1, {}, {});
#undef CSTEP
#undef PHASE

  // epilogue: D layout col=lane&15, row=(lane>>4)*4+reg (m89-verified)
#pragma unroll
  for (int mb = 0; mb < 4; ++mb)
#pragma unroll
    for (int nb = 0; nb < 4; ++nb)
#pragma unroll
      for (int r = 0; r < 4; ++r) {
        int rg = m0 + wm * 64 + mb * 16 + (l >> 4) * 4 + r;
        int cg = n0 + wn * 64 + nb * 16 + (l & 15);
        float vl = acc[mb][nb][r] * out_scale;
        if (WRITE_F32)
          ((float*)Cout)[(size_t)rg * DIMN + cg] = vl;
        else
          ((unsigned short*)Cout)[(size_t)rg * DIMN + cg] = f2bf(vl);
      }
}

// ---------------- fused flash attention (unchanged) ----------------
__global__ __launch_bounds__(256) void attn_kernel(
    const unsigned short* __restrict__ q, const unsigned short* __restrict__ k,
    const unsigned short* __restrict__ v, unsigned short* __restrict__ o) {
  __shared__ unsigned short Qs[64 * 72];
  __shared__ unsigned short Ks[64 * 72];
  __shared__ unsigned short Vt[64 * 72];
  __shared__ unsigned short Ps[4][16 * 72];

  const int t = threadIdx.x, l = t & 63, w = t >> 6;
  const int h = blockIdx.x >> 4;
  const int q0 = (blockIdx.x & 15) * 64;
  const int skey = t >> 2;
  const int sd = (t & 3) * 16;

  {
    const unsigned short* src = q + (size_t)(q0 + skey) * DIMN + h * 64 + sd;
    uint4 a = *(const uint4*)src;
    uint4 b = *(const uint4*)(src + 8);
    *(uint4*)&Qs[skey * 72 + sd] = a;
    *(uint4*)&Qs[skey * 72 + sd + 8] = b;
  }
  __syncthreads();
  bf16x8 qf[2];
#pragma unroll
  for (int kh = 0; kh < 2; ++kh)
    qf[kh] = *(const bf16x8*)&Qs[(w * 16 + (l & 15)) * 72 + (l >> 4) * 8 + kh * 32];

  float m_run[4] = {-1e30f, -1e30f, -1e30f, -1e30f};
  float l_run[4] = {0.f, 0.f, 0.f, 0.f};
  f32x4 oacc[4];
#pragma unroll
  for (int db = 0; db < 4; ++db) oacc[db] = (f32x4){0.f, 0.f, 0.f, 0.f};

  for (int kv = 0; kv < 16; ++kv) {
    __syncthreads();
    {
      const unsigned short* ksrc = k + (size_t)(kv * 64 + skey) * DIMN + h * 64 + sd;
      uint4 a = *(const uint4*)ksrc;
      uint4 b = *(const uint4*)(ksrc + 8);
      *(uint4*)&Ks[skey * 72 + sd] = a;
      *(uint4*)&Ks[skey * 72 + sd + 8] = b;
      const unsigned short* vsrc = v + (size_t)(kv * 64 + skey) * DIMN + h * 64 + sd;
      uint4 c = *(const uint4*)vsrc;
      uint4 d = *(const uint4*)(vsrc + 8);
      const unsigned short* cs = (const unsigned short*)&c;
      const unsigned short* ds = (const unsigned short*)&d;
#pragma unroll
      for (int j = 0; j < 8; ++j) Vt[(sd + j) * 72 + skey] = cs[j];
#pragma unroll
      for (int j = 0; j < 8; ++j) Vt[(sd + 8 + j) * 72 + skey] = ds[j];
    }
    __syncthreads();

    f32x4 sAcc[4];
#pragma unroll
    for (int nb = 0; nb < 4; ++nb) sAcc[nb] = (f32x4){0.f, 0.f, 0.f, 0.f};
#pragma unroll
    for (int kh = 0; kh < 2; ++kh) {
#pragma unroll
      for (int nb = 0; nb < 4; ++nb) {
        bf16x8 kf = *(const bf16x8*)&Ks[(nb * 16 + (l & 15)) * 72 + (l >> 4) * 8 + kh * 32];
        sAcc[nb] = MFMA16(qf[kh], kf, sAcc[nb]);
      }
    }

    float sc[4], mx[4];
#pragma unroll
    for (int r = 0; r < 4; ++r) {
      float mv = fmaxf(fmaxf(sAcc[0][r], sAcc[1][r]), fmaxf(sAcc[2][r], sAcc[3][r]));
      mv = fmaxf(mv, __shfl_xor(mv, 1));
      mv = fmaxf(mv, __shfl_xor(mv, 2));
      mv = fmaxf(mv, __shfl_xor(mv, 4));
      mv = fmaxf(mv, __shfl_xor(mv, 8));
      float mn = fmaxf(m_run[r], mv);
      sc[r] = __expf(m_run[r] - mn);
      m_run[r] = mn;
      mx[r] = mn;
    }
#pragma unroll
    for (int nb = 0; nb < 4; ++nb) {
      f32x4 sv = sAcc[nb];
#pragma unroll
      for (int r = 0; r < 4; ++r) sv[r] = __expf(sv[r] - mx[r]);
      sAcc[nb] = sv;
    }
#pragma unroll
    for (int r = 0; r < 4; ++r) {
      float ls = sAcc[0][r] + sAcc[1][r] + sAcc[2][r] + sAcc[3][r];
      ls += __shfl_xor(ls, 1);
      ls += __shfl_xor(ls, 2);
      ls += __shfl_xor(ls, 4);
      ls += __shfl_xor(ls, 8);
      l_run[r] = l_run[r] * sc[r] + ls;
    }
#pragma unroll
    for (int db = 0; db < 4; ++db) {
      f32x4 ov = oacc[db];
#pragma unroll
      for (int r = 0; r < 4; ++r) ov[r] *= sc[r];
      oacc[db] = ov;
    }

#pragma unroll
    for (int nb = 0; nb < 4; ++nb)
#pragma unroll
      for (int r = 0; r < 4; ++r)
        Ps[w][((l >> 4) * 4 + r) * 72 + nb * 16 + (l & 15)] = f2bf(sAcc[nb][r]);

#pragma unroll
    for (int kh = 0; kh < 2; ++kh) {
      bf16x8 pf = *(const bf16x8*)&Ps[w][(l & 15) * 72 + (l >> 4) * 8 + kh * 32];
#pragma unroll
      for (int db = 0; db < 4; ++db) {
        bf16x8 vf = *(const bf16x8*)&Vt[(db * 16 + (l & 15)) * 72 + (l >> 4) * 8 + kh * 32];
        oacc[db] = MFMA16(pf, vf, oacc[db]);
      }
    }
  }

#pragma unroll
  for (int db = 0; db < 4; ++db)
#pragma unroll
    for (int r = 0; r < 4; ++r) {
      float vl = oacc[db][r] / l_run[r];
      int rg = q0 + w * 16 + (l >> 4) * 4 + r;
      int cg = h * 64 + db * 16 + (l & 15);
      o[(size_t)rg * DIMN + cg] = f2bf(vl);
    }
}

extern "C" void kernel_launch(void* const* d_in, const int* in_sizes, int n_in,
                              void* d_out, int out_size, void* d_ws, size_t ws_size,
                              hipStream_t stream) {
  const float* x  = (const float*)d_in[0];
  const float* wq = (const float*)d_in[1];
  const float* wk = (const float*)d_in[2];
  const float* wv = (const float*)d_in[3];
  const float* wo = (const float*)d_in[4];

  char* ws = (char*)d_ws;
  const size_t MB16 = (size_t)16 * 1024 * 1024;
  unsigned short* xb = (unsigned short*)(ws);
  unsigned short* qb = (unsigned short*)(ws + 1 * MB16);
  unsigned short* kb = (unsigned short*)(ws + 2 * MB16);
  unsigned short* vb = (unsigned short*)(ws + 3 * MB16);
  unsigned short* ab = (unsigned short*)(ws + 4 * MB16);

  cvt_bf16_kernel<<<4096, 256, 0, stream>>>(x, xb);
  gemm_bf16<0><<<256, 512, 0, stream>>>(xb, wq, qb, 0.125f);  // softmax scale folded
  gemm_bf16<0><<<256, 512, 0, stream>>>(xb, wk, kb, 1.0f);
  gemm_bf16<0><<<256, 512, 0, stream>>>(xb, wv, vb, 1.0f);
  attn_kernel<<<2048, 256, 0, stream>>>(qb, kb, vb, ab);
  gemm_bf16<1><<<256, 512, 0, stream>>>(ab, wo, d_out, 1.0f);
}